// Round 9
// baseline (342.781 us; speedup 1.0000x reference)
//
#include <hip/hip_runtime.h>
#include <hip/hip_bf16.h>

typedef __bf16 bf16_t;
typedef __attribute__((ext_vector_type(8))) __bf16 bf16x8;
typedef __attribute__((ext_vector_type(4))) __bf16 bf16x4;
typedef __attribute__((ext_vector_type(4))) float f32x4;

#define NPOS 38416  // 196*196
#define NPAD 224    // 7*32
#define KSTR 40     // kf row stride (bf16): 80B = 20 banks -> 2-way (free)
#define VSTR 232    // vts/pb row stride (bf16): 464B, 16B-aligned, 2-way

__device__ __forceinline__ void async_copy16(const bf16_t* g, bf16_t* l) {
  __builtin_amdgcn_global_load_lds((const __attribute__((address_space(1))) void*)g,
                                   (__attribute__((address_space(3))) void*)l, 16, 0, 0);
}

// ---------------- fused preprocessing: cast_x U transpose(Wqkv) U transpose(Wproj) U bias_gather
// All four mutually independent; one launch replaces four (3 fewer launch
// gaps; the small transposes/gather co-fill the machine with the cast).
// Bounds audit: cast covers exactly 12544*256 float4 = all of x; Wqkv ids
// [0,3072) -> rows<1024, cols<3072; Wproj ids [0,1024); bias guard pos<NPOS.
// __syncthreads in transpose_tile is block-uniform (branch on blockIdx only).
__device__ __forceinline__ void transpose_tile(const float* __restrict__ src,
                                               bf16_t* __restrict__ dst,
                                               int K, int Ncols, int bx, int by,
                                               float (*tile)[33], int t) {
  int tx = t & 31, ty = t >> 5;
  for (int r = ty; r < 32; r += 8)
    tile[r][tx] = src[(size_t)(by * 32 + r) * Ncols + bx * 32 + tx];
  __syncthreads();
  for (int r = ty; r < 32; r += 8)
    dst[(size_t)(bx * 32 + r) * K + by * 32 + tx] = (bf16_t)tile[tx][r];
}

__global__ __launch_bounds__(256) void prep_kernel(
    const float* __restrict__ x, bf16_t* __restrict__ xb,
    const float* __restrict__ Wqkv, bf16_t* __restrict__ wqkvT,
    const float* __restrict__ Wproj, bf16_t* __restrict__ wprojT,
    const float* __restrict__ rpk, const int* __restrict__ rel_idx,
    float* __restrict__ bias) {
  __shared__ float tile[32][33];
  const int bid = blockIdx.x;
  const int t = threadIdx.x;
  if (bid < 12544) {
    const int i = bid * 256 + t;
    float4 v = ((const float4*)x)[i];
    bf16x4 o;
    o[0] = (bf16_t)v.x; o[1] = (bf16_t)v.y; o[2] = (bf16_t)v.z; o[3] = (bf16_t)v.w;
    ((bf16x4*)xb)[i] = o;
  } else if (bid < 12544 + 3072) {
    const int id = bid - 12544;               // Wqkv tiles (96 x 32)
    transpose_tile(Wqkv, wqkvT, 1024, 3072, id % 96, id / 96, tile, t);
  } else if (bid < 12544 + 3072 + 1024) {
    const int id = bid - 15616;               // Wproj tiles (32 x 32)
    transpose_tile(Wproj, wprojT, 1024, 1024, id & 31, id >> 5, tile, t);
  } else {
    const int pos = (bid - 16640) * 256 + t;  // bias gather (151 blocks)
    if (pos < NPOS) {
      int idx = rel_idx[pos];
      const float* r = rpk + idx * 32;
#pragma unroll
      for (int h = 0; h < 32; ++h) bias[h * NPOS + pos] = r[h];
    }
  }
}

// ---------------- 256x128 bf16 GEMM, B^T input, K=1024 ----------------
// PROVEN structure (119.5 us gemm1): 512 threads / 8 waves (4x2 of 64x64).
// Double-buffered LDS (48 KiB -> 3 blocks/CU; cross-block overlap hides the
// barrier drain), ONE barrier per K-iter.  16B-chunk XOR swizzle.
// Bijective XCD-chunked block swizzle (FETCH -22%, time-neutral, kept).
// Do NOT retile to 128^2 (r4: FETCH doubles, +13 us).  8-phase restructures
// regressed twice (r1: 149 us, r2: 146 us) — this 2-phase form is the ceiling
// for this structure family on this shape.
template <int MODE>
__global__ __launch_bounds__(512, 4) void gemm_bt_kernel(
    const bf16_t* __restrict__ A, const bf16_t* __restrict__ Bt,
    bf16_t* __restrict__ qo, bf16_t* __restrict__ ko, bf16_t* __restrict__ vto,
    float* __restrict__ fo, const float* __restrict__ bp) {
  constexpr int K = 1024;
  constexpr int CH = 384 * 32;  // bf16 elems per buffer: (256 A-rows + 128 B-rows) x 32
  __shared__ alignas(16) bf16_t S[2][CH];
  const int t = threadIdx.x;
  const int lane = t & 63;
  const int quad = lane >> 4;
  const int l16 = lane & 15;
  const int wave = t >> 6;

  // T1: bijective XCD-chunked swizzle (m204)
  const int GX = gridDim.x;
  const int nwg = GX * gridDim.y;
  const int lin = blockIdx.y * GX + blockIdx.x;
  const int qch = nwg >> 3, rch = nwg & 7;
  const int xcd = lin & 7, off = lin >> 3;
  const int swz = (xcd < rch ? xcd * (qch + 1) : rch * (qch + 1) + (xcd - rch) * qch) + off;
  const int m0 = (swz / GX) * 256, n0 = (swz % GX) * 128;

  const int wr = (wave >> 1) * 64, wc = (wave & 1) * 64;

  // staging: 1536 16B-chunks; thread t covers c = t, t+512, t+1024
  const bf16_t* gp[3];
  int lofs[3];
#pragma unroll
  for (int j = 0; j < 3; ++j) {
    const int c = t + j * 512;
    const int row = c >> 2;
    const int sc = (c & 3) ^ ((c >> 3) & 3);
    gp[j] = (row < 256) ? A + (size_t)(m0 + row) * K + sc * 8
                        : Bt + (size_t)(n0 + row - 256) * K + sc * 8;
    lofs[j] = c * 8;
  }

  // fragment reads: global chunk `quad` lives at phys chunk quad ^ ((l16>>1)&3)
  const int qa = quad ^ ((l16 >> 1) & 3);

  const f32x4 vzero = {0.f, 0.f, 0.f, 0.f};
  f32x4 acc[4][4];
#pragma unroll
  for (int i = 0; i < 4; ++i)
#pragma unroll
    for (int j = 0; j < 4; ++j) acc[i][j] = vzero;

  // preload k-tile 0 into S[0]
#pragma unroll
  for (int j = 0; j < 3; ++j) async_copy16(gp[j], &S[0][lofs[j]]);

  for (int it = 0; it < K / 32; ++it) {
    __syncthreads();  // drains loads issued one full iteration ago
    const bf16_t* Sb = S[it & 1];
    if (it + 1 < K / 32) {
      bf16_t* Sn = S[(it + 1) & 1];
      const int kt = (it + 1) * 32;
#pragma unroll
      for (int j = 0; j < 3; ++j) async_copy16(gp[j] + kt, Sn + lofs[j]);
    }
    const bf16_t* As = Sb;
    const bf16_t* Bs = Sb + 256 * 32;
    bf16x8 af[4], bfr[4];
#pragma unroll
    for (int i = 0; i < 4; ++i) {
      af[i] = *(const bf16x8*)(As + (wr + i * 16 + l16) * 32 + qa * 8);
      bfr[i] = *(const bf16x8*)(Bs + (wc + i * 16 + l16) * 32 + qa * 8);
    }
#pragma unroll
    for (int i = 0; i < 4; ++i)
#pragma unroll
      for (int j = 0; j < 4; ++j)
        acc[i][j] = __builtin_amdgcn_mfma_f32_16x16x32_bf16(af[i], bfr[j], acc[i][j], 0, 0, 0);
  }

  if (MODE == 0) {
    const float qscale = 0.17677669529663687f;  // 1/sqrt(32)
    const int which = n0 >> 10;                 // uniform per block (1024 % 128 == 0)
#pragma unroll
    for (int i = 0; i < 4; ++i) {
      const int rb = m0 + wr + i * 16 + quad * 4;
#pragma unroll
      for (int j = 0; j < 4; ++j) {
        const int c = n0 + wc + j * 16 + l16;
        const int h = (c >> 5) & 31, d = c & 31;
#pragma unroll
        for (int r = 0; r < 4; ++r) {
          const int rg = rb + r;
          const int b = rg / 196, n = rg - b * 196;
          const float v = acc[i][j][r];
          if (which == 0)
            qo[(((size_t)b * 32 + h) * 196 + n) * 32 + d] = (bf16_t)(v * qscale);
          else if (which == 1)
            ko[(((size_t)b * 32 + h) * 196 + n) * 32 + d] = (bf16_t)v;
          else
            vto[(((size_t)b * 32 + h) * 32 + d) * 196 + n] = (bf16_t)v;
        }
      }
    }
  } else {
#pragma unroll
    for (int i = 0; i < 4; ++i) {
      const int rb = m0 + wr + i * 16 + quad * 4;
#pragma unroll
      for (int j = 0; j < 4; ++j) {
        const int c = n0 + wc + j * 16 + l16;
        const float bias_c = bp[c];
#pragma unroll
        for (int r = 0; r < 4; ++r)
          fo[(size_t)(rb + r) * 1024 + c] = acc[i][j][r] + bias_c;
      }
    }
  }
}

// ---------------- attention: one block per (b,h) ----------------
// r8 package (unchanged; 341.8 us best): T14 bias software-pipeline with
// ping-pong register buffers, T5 setprio around MFMA clusters, tree
// reductions.
#define LOADB(Q0, BV)                                                         \
  _Pragma("unroll") for (int ct = 0; ct < 13; ++ct) {                         \
    const int col = ct * 16 + l16;                                            \
    _Pragma("unroll") for (int r = 0; r < 4; ++r) {                           \
      int br = (Q0) + quad * 4 + r;                                           \
      if (br > 195) br = 195;                                                 \
      BV[ct][r] = (col < 196) ? bg[br * 196 + col] : 0.f;                     \
    }                                                                         \
  }

#define AITER(Q0, BVC, QN, BVN, PREF)                                         \
  {                                                                           \
    const int q0_ = (Q0);                                                     \
    int qrow_ = q0_ + l16;                                                    \
    if (qrow_ > 195) qrow_ = 195;                                             \
    const bf16x8 aq_ = *(const bf16x8*)(qg + qrow_ * 32 + quad * 8);          \
    f32x4 s[13];                                                              \
    __builtin_amdgcn_s_setprio(1);                                            \
    _Pragma("unroll") for (int ct = 0; ct < 13; ++ct) {                       \
      const bf16x8 bk_ = *(const bf16x8*)(kf + (ct * 16 + l16) * KSTR + quad * 8); \
      s[ct] = __builtin_amdgcn_mfma_f32_16x16x32_bf16(aq_, bk_, vzero, 0, 0, 0); \
    }                                                                         \
    __builtin_amdgcn_s_setprio(0);                                            \
    _Pragma("unroll") for (int ct = 0; ct < 13; ++ct) {                       \
      const int col = ct * 16 + l16;                                          \
      _Pragma("unroll") for (int r = 0; r < 4; ++r) {                         \
        if (col < 196) s[ct][r] += BVC[ct][r];                                \
        else s[ct][r] = -1e30f;                                               \
      }                                                                       \
    }                                                                         \
    float mx[4], inv[4];                                                      \
    _Pragma("unroll") for (int r = 0; r < 4; ++r) {                           \
      float p0_ = fmaxf(s[0][r], s[1][r]), p1_ = fmaxf(s[2][r], s[3][r]);     \
      float p2_ = fmaxf(s[4][r], s[5][r]), p3_ = fmaxf(s[6][r], s[7][r]);     \
      float p4_ = fmaxf(s[8][r], s[9][r]), p5_ = fmaxf(s[10][r], s[11][r]);   \
      float m_ = fmaxf(fmaxf(fmaxf(p0_, p1_), fmaxf(p2_, p3_)),               \
                       fmaxf(fmaxf(p4_, p5_), s[12][r]));                     \
      m_ = fmaxf(m_, __shfl_xor(m_, 1));                                      \
      m_ = fmaxf(m_, __shfl_xor(m_, 2));                                      \
      m_ = fmaxf(m_, __shfl_xor(m_, 4));                                      \
      m_ = fmaxf(m_, __shfl_xor(m_, 8));                                      \
      mx[r] = m_;                                                             \
    }                                                                         \
    _Pragma("unroll") for (int ct = 0; ct < 13; ++ct)                         \
      _Pragma("unroll") for (int r = 0; r < 4; ++r)                           \
        s[ct][r] = __expf(s[ct][r] - mx[r]);                                  \
    _Pragma("unroll") for (int r = 0; r < 4; ++r) {                           \
      float a0_ = (s[0][r] + s[1][r]) + (s[2][r] + s[3][r]);                  \
      float a1_ = (s[4][r] + s[5][r]) + (s[6][r] + s[7][r]);                  \
      float a2_ = (s[8][r] + s[9][r]) + (s[10][r] + s[11][r]);                \
      float sum_ = a0_ + a1_ + (a2_ + s[12][r]);                              \
      sum_ += __shfl_xor(sum_, 1);                                            \
      sum_ += __shfl_xor(sum_, 2);                                            \
      sum_ += __shfl_xor(sum_, 4);                                            \
      sum_ += __shfl_xor(sum_, 8);                                            \
      inv[r] = 1.f / sum_;                                                    \
    }                                                                         \
    _Pragma("unroll") for (int ct = 0; ct < 13; ++ct) {                       \
      const int col = ct * 16 + l16;                                          \
      _Pragma("unroll") for (int r = 0; r < 4; ++r)                           \
        pw[(quad * 4 + r) * VSTR + col] = (bf16_t)s[ct][r];                   \
    }                                                                         \
    if (lane < 32) {                                                          \
      const bf16x8 z8_ = {};                                                  \
      *(bf16x8*)(pw + (lane >> 1) * VSTR + 208 + (lane & 1) * 8) = z8_;       \
    }                                                                         \
    if (PREF) { LOADB((QN), BVN); }                                           \
    _Pragma("unroll") for (int dt = 0; dt < 2; ++dt) {                        \
      f32x4 o_ = vzero;                                                       \
      __builtin_amdgcn_s_setprio(1);                                          \
      _Pragma("unroll") for (int kk2 = 0; kk2 < 7; ++kk2) {                   \
        const bf16x8 ap_ = *(const bf16x8*)(pw + l16 * VSTR + kk2 * 32 + quad * 8); \
        const bf16x8 bv2_ = *(const bf16x8*)(vts + (dt * 16 + l16) * VSTR + kk2 * 32 + quad * 8); \
        o_ = __builtin_amdgcn_mfma_f32_16x16x32_bf16(ap_, bv2_, o_, 0, 0, 0); \
      }                                                                       \
      __builtin_amdgcn_s_setprio(0);                                          \
      const int d_ = dt * 16 + l16;                                           \
      _Pragma("unroll") for (int r = 0; r < 4; ++r) {                         \
        const int n_ = q0_ + quad * 4 + r;                                    \
        if (n_ < 196)                                                         \
          attn_out[(((size_t)b * 196 + n_) * 32 + h) * 32 + d_] =             \
              (bf16_t)(o_[r] * inv[r]);                                       \
      }                                                                       \
    }                                                                         \
  }

__global__ __launch_bounds__(256, 2) void attn_kernel(
    const bf16_t* __restrict__ q, const bf16_t* __restrict__ kmat,
    const bf16_t* __restrict__ vtg, const float* __restrict__ bias,
    bf16_t* __restrict__ attn_out) {
  __shared__ alignas(16) bf16_t kf[NPAD * KSTR];    // K rows [n][d], stride 40
  __shared__ alignas(16) bf16_t vts[32 * VSTR];     // V^T [d][n], stride 232
  __shared__ alignas(16) bf16_t pb[4][16 * VSTR];   // per-wave unnormalized P

  const int t = threadIdx.x;
  const int lane = t & 63;
  const int quad = lane >> 4, l16 = lane & 15;
  const int wave = t >> 6;
  const int bh = blockIdx.x;                        // b-major
  const int b = bh >> 5, h = bh & 31;
  const bf16_t* qg = q + (size_t)bh * (196 * 32);
  const bf16_t* kg = kmat + (size_t)bh * (196 * 32);
  const bf16_t* vg = vtg + (size_t)bh * (32 * 196);
  const float* bg = bias + (size_t)h * NPOS;

  // issue chunk-0 bias loads BEFORE staging: they land during staging
  float bvA[13][4], bvB[13][4];
  LOADB(wave * 16, bvA);

  {
    const uint4* src = (const uint4*)kg;
    uint4* dst = (uint4*)kf;  // row r -> uint4 slots [r*5, r*5+3]; slot r*5+4 unused
    for (int c = t; c < 784; c += 256) dst[(c >> 2) * 5 + (c & 3)] = src[c];
    const uint4 z4 = {0u, 0u, 0u, 0u};
    if (t < 112) {  // zero pad rows 196..223, chunks 0..3
      int r = 196 + (t >> 2), ch = t & 3;
      dst[r * 5 + ch] = z4;
    }
    const uint2 z2 = {0u, 0u};
    for (int i = t; i < 1792; i += 256) {  // 32 rows x 56 x 8B (stride VSTR)
      int d = i / 56, c = i - d * 56;
      uint2 val = (c < 49) ? ((const uint2*)(vg + d * 196))[c] : z2;
      ((uint2*)(vts + d * VSTR))[c] = val;
    }
  }
  __syncthreads();

  const f32x4 vzero = {0.f, 0.f, 0.f, 0.f};
  bf16_t* pw = &pb[wave][0];

  // chunks ch = wave, wave+4, wave+8, wave+12 (<13); explicit unroll with
  // ping-pong bias buffers (static register indexing)
  AITER(wave * 16, bvA, (wave + 4) * 16, bvB, true);
  AITER((wave + 4) * 16, bvB, (wave + 8) * 16, bvA, true);
  AITER((wave + 8) * 16, bvA, (wave + 12) * 16, bvB, (wave + 12 < 13));
  if (wave + 12 < 13)
    AITER((wave + 12) * 16, bvB, 0, bvA, false);
}

extern "C" void kernel_launch(void* const* d_in, const int* in_sizes, int n_in,
                              void* d_out, int out_size, void* d_ws, size_t ws_size,
                              hipStream_t stream) {
  (void)in_sizes; (void)n_in; (void)out_size; (void)ws_size;
  const float* x = (const float*)d_in[0];
  const float* Wqkv = (const float*)d_in[1];
  const float* Wproj = (const float*)d_in[2];
  const float* bproj = (const float*)d_in[3];
  const float* rpk = (const float*)d_in[4];
  const int* rel_idx = (const int*)d_in[5];
  float* out = (float*)d_out;

  char* ws = (char*)d_ws;
  bf16_t* xb = (bf16_t*)(ws + 0);                  // 25,690,112 B ; reused as attn_out
  bf16_t* wqkvT = (bf16_t*)(ws + 25690112);        //  6,291,456 B
  bf16_t* wprojT = (bf16_t*)(ws + 31981568);       //  2,097,152 B
  bf16_t* q = (bf16_t*)(ws + 34078720);            // 25,690,112 B
  bf16_t* kk = (bf16_t*)(ws + 59768832);           // 25,690,112 B
  bf16_t* vt = (bf16_t*)(ws + 85458944);           // 25,690,112 B
  float* bias = (float*)(ws + 111149056);          //  4,917,248 B  (total ~116 MB)
  bf16_t* attn = xb;                               // xb is dead after GEMM1

  prep_kernel<<<16791, 256, 0, stream>>>(x, xb, Wqkv, wqkvT, Wproj, wprojT,
                                         rpk, rel_idx, bias);
  gemm_bt_kernel<0><<<dim3(24, 49), 512, 0, stream>>>(xb, wqkvT, q, kk, vt, nullptr, nullptr);
  attn_kernel<<<2048, 256, 0, stream>>>(q, kk, vt, bias, attn);
  gemm_bt_kernel<1><<<dim3(8, 49), 512, 0, stream>>>(attn, wprojT, nullptr, nullptr, nullptr, out, bproj);
}